// Round 7
// baseline (752.117 us; speedup 1.0000x reference)
//
#include <hip/hip_runtime.h>
#include <math.h>

typedef unsigned short u16;
typedef unsigned short u16x4 __attribute__((ext_vector_type(4)));
typedef unsigned short u16x8 __attribute__((ext_vector_type(8)));
typedef short s16x8 __attribute__((ext_vector_type(8)));
typedef float f32x4 __attribute__((ext_vector_type(4)));

constexpr int NN   = 10000;   // nodes
constexpr int MP   = 10112;   // nodes padded to multiple of 128
constexpr int IN   = 256;
constexpr int TD   = 768;
constexpr int CD   = 3328;    // IN + 4*TD
constexpr int HD   = 1024;
constexpr int HCH  = 256;     // HD/4 heads
constexpr int SDIM = 128;
constexpr int KSK  = 20;
constexpr int ACAP = 256;     // LDS alpha capacity (edges) in fused GAT
constexpr float LN_EPS = 1e-5f;
constexpr float COS_EPS = 1e-8f;
constexpr float NEG_SLOPE = 0.2f;

__device__ __forceinline__ float warp_sum(float v){
#pragma unroll
  for (int o=1;o<64;o<<=1) v += __shfl_xor(v,o);
  return v;
}
__device__ __forceinline__ float warp_max(float v){
#pragma unroll
  for (int o=1;o<64;o<<=1) v = fmaxf(v, __shfl_xor(v,o));
  return v;
}
__device__ __forceinline__ u16 f2b(float f){
  unsigned u = __float_as_uint(f);
  return (u16)((u + 0x7fffu + ((u>>16)&1u)) >> 16);
}
__device__ __forceinline__ float b2f(u16 b){ return __uint_as_float(((unsigned)b)<<16); }

#define GLDS(g, l) __builtin_amdgcn_global_load_lds( \
    (const __attribute__((address_space(1))) void*)(g), \
    (__attribute__((address_space(3))) void*)(l), 16, 0, 0)

// ---------------- bf16 MFMA GEMM: C[M,N] = A[Mpad,K](bf16) @ Bt[N,K]^T ------
// grid (N/128, Mpad/128, Z), block 256 (4 waves, 2x2, 64x64 each). K%32==0.
// 2-phase double-buffered LDS prefetch (proven BK=32, 32KB LDS) + XCD swizzle.
// Epilogue stages C through LDS for coalesced 16B stores.
// NOTE (R2 post-mortem): do NOT fuse device-scope ATOMICS into this epilogue —
// they poison L2 (FETCH +26MB, 95->126us measured). NON-atomic partial stores
// are fine (R7): each block owns its (row, head, parity) slot exclusively.
// es/ed fusion: with a_s/a_d/esp/edp set (bf16 path), block computes partial
// GAT logits over its 128 cols (= half a head) and stores them to
// esp[row*8 + head*2 + parity] / edp[...] with plain stores.
__global__ __launch_bounds__(256) void k_gemm_bf16(
    const u16* __restrict__ A, long Az,
    const u16* __restrict__ B0c, const u16* __restrict__ B1c,
    const u16* __restrict__ B2c, const u16* __restrict__ B3c,
    const float* __restrict__ bias0, const float* __restrict__ bias1,
    const float* __restrict__ bias2, const float* __restrict__ bias3,
    float* __restrict__ Cf, int ldcf,
    u16* __restrict__ Cb, int ldcb, long Cbz,
    const float* __restrict__ demb, const int* __restrict__ dids,
    int M, int K, int relu,
    const float* __restrict__ a_s, const float* __restrict__ a_d,
    float* __restrict__ esp, float* __restrict__ edp)
{
  __shared__ __align__(16) u16 smem[16384];   // 32KB: staging OR C-tile
  // staging partition: A buf0 @0, A buf1 @4096, B buf0 @8192, B buf1 @12288
  const int z = blockIdx.z;
  const u16* Bt = (z==0)? B0c : (z==1)? B1c : (z==2)? B2c : B3c;
  const float* bias = (z==0)? bias0 : (z==1)? bias1 : (z==2)? bias2 : bias3;
  const u16* Ab = A + (size_t)z * (size_t)Az;

  const int tid = threadIdx.x;
  const int wave = tid >> 6, lane = tid & 63;
  const int wr = wave >> 1, wc = wave & 1;

  // bijective XCD swizzle (m204)
  const int nwg  = gridDim.x * gridDim.y;
  const int orig = blockIdx.y * gridDim.x + blockIdx.x;
  const int q = nwg >> 3, r = nwg & 7;
  const int xcd = orig & 7, loc = orig >> 3;
  const int wg = (xcd < r ? xcd*(q+1) : r*(q+1) + (xcd-r)*q) + loc;
  const int bx = wg % gridDim.x, byy = wg / gridDim.x;
  const size_t bm = (size_t)byy * 128;
  const size_t bn = (size_t)bx * 128;

  f32x4 acc[4][4];
#pragma unroll
  for (int m=0;m<4;m++)
#pragma unroll
    for (int n=0;n<4;n++) acc[m][n] = f32x4{0.f,0.f,0.f,0.f};

  const int srow = tid >> 2;
  const int scol = (tid & 3) * 8;
  const u16* ga0 = Ab + (bm + srow) * (size_t)K + scol;
  const u16* ga1 = ga0 + (size_t)64 * K;
  const u16* gb0 = Bt + (bn + srow) * (size_t)K + scol;
  const u16* gb1 = gb0 + (size_t)64 * K;

  auto stage = [&](int buf, int k0){
    GLDS(ga0 + k0, smem + buf*4096 + wave*512);
    GLDS(ga1 + k0, smem + buf*4096 + 2048 + wave*512);
    GLDS(gb0 + k0, smem + 8192 + buf*4096 + wave*512);
    GLDS(gb1 + k0, smem + 8192 + buf*4096 + 2048 + wave*512);
  };

  const int ar = wr*64 + (lane & 15);     // A row within tile
  const int br = wc*64 + (lane & 15);     // B col within tile
  const int kg = (lane >> 4) * 8;         // k group

  const int nt = K >> 5;
  stage(0, 0);
  __syncthreads();                         // drains vmcnt(0)
  int cur = 0;
  for (int t = 0; t < nt; ++t){
    if (t+1 < nt) stage(cur^1, (t+1)*32);  // async prefetch overlaps MFMAs
    s16x8 a[4], b[4];
#pragma unroll
    for (int m=0;m<4;m++) a[m] = *(const s16x8*)(smem + cur*4096 + (ar + m*16)*32 + kg);
#pragma unroll
    for (int n=0;n<4;n++) b[n] = *(const s16x8*)(smem + 8192 + cur*4096 + (br + n*16)*32 + kg);
#pragma unroll
    for (int m=0;m<4;m++)
#pragma unroll
      for (int n=0;n<4;n++)
        acc[m][n] = __builtin_amdgcn_mfma_f32_16x16x32_bf16(a[m], b[n], acc[m][n], 0, 0, 0);
    __syncthreads();                       // one barrier/iter, drains prefetch
    cur ^= 1;
  }
  // after the loop's final barrier, smem is dead -> reuse for the C tile

  const int cl0 = wc*64 + (lane & 15);     // local col base
  if (Cb){
    // bf16 path: full [128][128] tile in LDS, then 8 coalesced 16B stores/thread
#pragma unroll
    for (int m=0;m<4;m++)
#pragma unroll
      for (int j=0;j<4;j++){
        int rl = wr*64 + ((lane >> 4) * 4) + m*16 + j;
#pragma unroll
        for (int n=0;n<4;n++){
          int cl = cl0 + n*16;
          float v = acc[m][n][j];
          if (bias) v += bias[bn + cl];
          if (relu) v = fmaxf(v, 0.f);
          smem[rl*128 + cl] = f2b(v);
        }
      }
    __syncthreads();
    float as8[8], ad8[8];
    if (esp){
      int cb2 = (int)bn + (tid & 15) * 8;   // a_s is [4][256] flat = [HD] floats
#pragma unroll
      for (int k2=0;k2<8;k2++){ as8[k2]=a_s[cb2+k2]; ad8[k2]=a_d[cb2+k2]; }
    }
    const int head = (int)(bn >> 8);
    const int par  = (int)(bn >> 7) & 1;    // which 128-col half of the head
#pragma unroll
    for (int it=0; it<8; ++it){
      int rl = it*16 + (tid >> 4);
      int cl = (tid & 15) * 8;
      u16x8 vv = *(const u16x8*)(smem + rl*128 + cl);
      *(u16x8*)(Cb + (size_t)z*Cbz + (bm + rl)*(size_t)ldcb + bn + cl) = vv;
      if (esp){
        float ps=0.f, pd=0.f;
#pragma unroll
        for (int k2=0;k2<8;k2++){
          float f = b2f(vv[k2]);
          ps = fmaf(f, as8[k2], ps);
          pd = fmaf(f, ad8[k2], pd);
        }
        ps += __shfl_xor(ps,1); ps += __shfl_xor(ps,2);
        ps += __shfl_xor(ps,4); ps += __shfl_xor(ps,8);
        pd += __shfl_xor(pd,1); pd += __shfl_xor(pd,2);
        pd += __shfl_xor(pd,4); pd += __shfl_xor(pd,8);
        int rg = (int)bm + rl;
        if ((tid&15)==0 && rg < M){
          esp[(size_t)rg*8 + head*2 + par] = ps;   // plain store, block-owned slot
          edp[(size_t)rg*8 + head*2 + par] = pd;
        }
      }
    }
  } else if (Cf){
    // f32 path: two [64][128] passes through LDS, 16B f32x4 stores
    float* ctf = (float*)smem;
#pragma unroll
    for (int p=0;p<2;p++){
      if (wr == p){
#pragma unroll
        for (int m=0;m<4;m++)
#pragma unroll
          for (int j=0;j<4;j++){
            int rl = ((lane >> 4) * 4) + m*16 + j;        // 0..63 in half
            int rg = (int)bm + p*64 + rl;
            const float* dbase = (demb && rg < M) ? demb + (size_t)dids[rg]*HD : nullptr;
#pragma unroll
            for (int n=0;n<4;n++){
              int cl = cl0 + n*16;
              float v = acc[m][n][j];
              if (bias) v += bias[bn + cl];
              if (dbase) v += dbase[bn + cl];
              if (relu) v = fmaxf(v, 0.f);
              ctf[rl*128 + cl] = v;
            }
          }
      }
      __syncthreads();
#pragma unroll
      for (int it=0; it<8; ++it){
        int rl = it*8 + (tid >> 5);
        int cl = (tid & 31) * 4;
        int rg = (int)bm + p*64 + rl;
        if (rg < M){
          float4 vv = *(const float4*)(ctf + rl*128 + cl);
          *(float4*)(Cf + (size_t)rg*ldcf + bn + cl) = vv;
        }
      }
      __syncthreads();
    }
  }
}

// ------- text GEMM: A is f32 (raw embeddings), converted to bf16 in-kernel --
// C[M,TD](bf16, z-offset cols) = f2b(Af32[M,K]) @ Bt[TD,K]^T + bias.
// One register set; wrA at iteration top (consumes regs drained by the prev
// barrier), reload immediately after. Saves the k_f2b8x4 pass + 62MB Aact.
// (R6: neutral vs R4 order — structure-bound at ~128us; do not re-grind.)
__global__ __launch_bounds__(256) void k_gemm_text(
    const float* __restrict__ A0, const float* __restrict__ A1,
    const float* __restrict__ A2, const float* __restrict__ A3,
    const u16* __restrict__ B0c, const u16* __restrict__ B1c,
    const u16* __restrict__ B2c, const u16* __restrict__ B3c,
    const float* __restrict__ bias0, const float* __restrict__ bias1,
    const float* __restrict__ bias2, const float* __restrict__ bias3,
    u16* __restrict__ Cb, int ldcb, long Cbz, int M, int K)
{
  __shared__ __align__(16) u16 smem[16384];   // 32KB: staging OR C-tile
  const int z = blockIdx.z;
  const float* Af = (z==0)? A0 : (z==1)? A1 : (z==2)? A2 : A3;
  const u16* Bt = (z==0)? B0c : (z==1)? B1c : (z==2)? B2c : B3c;
  const float* bias = (z==0)? bias0 : (z==1)? bias1 : (z==2)? bias2 : bias3;

  const int tid = threadIdx.x;
  const int wave = tid >> 6, lane = tid & 63;
  const int wr = wave >> 1, wc = wave & 1;

  // bijective XCD swizzle (m204)
  const int nwg  = gridDim.x * gridDim.y;
  const int orig = blockIdx.y * gridDim.x + blockIdx.x;
  const int q = nwg >> 3, r = nwg & 7;
  const int xcd = orig & 7, loc = orig >> 3;
  const int wg = (xcd < r ? xcd*(q+1) : r*(q+1) + (xcd-r)*q) + loc;
  const int bx = wg % gridDim.x, byy = wg / gridDim.x;
  const size_t bm = (size_t)byy * 128;
  const size_t bn = (size_t)bx * 128;

  f32x4 acc[4][4];
#pragma unroll
  for (int m=0;m<4;m++)
#pragma unroll
    for (int n=0;n<4;n++) acc[m][n] = f32x4{0.f,0.f,0.f,0.f};

  // B staging via GLDS (unchanged layout: B buf0 @8192, buf1 @12288 u16)
  const int srow = tid >> 2;
  const int scol = (tid & 3) * 8;
  const u16* gb0 = Bt + (bn + srow) * (size_t)K + scol;
  const u16* gb1 = gb0 + (size_t)64 * K;
  auto stageB = [&](int buf, int k0){
    GLDS(gb0 + k0, smem + 8192 + buf*4096 + wave*512);
    GLDS(gb1 + k0, smem + 8192 + buf*4096 + 2048 + wave*512);
  };

  // A f32 reg staging: thread -> row r0l (0..127), col half c0l (0 or 16)
  const int r0l = tid >> 1;
  const int c0l = (tid & 1) * 16;
  int rr = (int)bm + r0l; if (rr > M-1) rr = M-1;   // pad rows clamp (never read)
  const float* ga = Af + (size_t)rr * (size_t)K + c0l;

  float4 av0, av1, av2, av3;                 // ONE register set
  auto ldA = [&](int k0){
    av0 = *(const float4*)(ga + k0);
    av1 = *(const float4*)(ga + k0 + 4);
    av2 = *(const float4*)(ga + k0 + 8);
    av3 = *(const float4*)(ga + k0 + 12);
  };
  auto wrA = [&](int buf){
    u16x8 o0, o1;
    o0[0]=f2b(av0.x); o0[1]=f2b(av0.y); o0[2]=f2b(av0.z); o0[3]=f2b(av0.w);
    o0[4]=f2b(av1.x); o0[5]=f2b(av1.y); o0[6]=f2b(av1.z); o0[7]=f2b(av1.w);
    o1[0]=f2b(av2.x); o1[1]=f2b(av2.y); o1[2]=f2b(av2.z); o1[3]=f2b(av2.w);
    o1[4]=f2b(av3.x); o1[5]=f2b(av3.y); o1[6]=f2b(av3.z); o1[7]=f2b(av3.w);
    *(u16x8*)(smem + buf*4096 + r0l*32 + c0l)     = o0;
    *(u16x8*)(smem + buf*4096 + r0l*32 + c0l + 8) = o1;
  };

  const int ar = wr*64 + (lane & 15);
  const int br = wc*64 + (lane & 15);
  const int kg = (lane >> 4) * 8;

  const int nt = K >> 5;
  // prologue: tile0 -> buf0 (regs consumed immediately), then tile1 -> regs
  ldA(0); stageB(0, 0); wrA(0);
  if (nt > 1) ldA(32);
  __syncthreads();                           // drains everything (vmcnt(0))
  int cur = 0;
  for (int t = 0; t < nt; ++t){
    if (t+1 < nt){
      wrA(cur^1);                            // regs drained by PREV barrier: no wait
      if (t+2 < nt) ldA((t+2)*32);           // reuse the set; full-iter slack
      stageB(cur^1, (t+1)*32);
    }
    s16x8 a[4], b[4];
#pragma unroll
    for (int m=0;m<4;m++) a[m] = *(const s16x8*)(smem + cur*4096 + (ar + m*16)*32 + kg);
#pragma unroll
    for (int n=0;n<4;n++) b[n] = *(const s16x8*)(smem + 8192 + cur*4096 + (br + n*16)*32 + kg);
#pragma unroll
    for (int m=0;m<4;m++)
#pragma unroll
      for (int n=0;n<4;n++)
        acc[m][n] = __builtin_amdgcn_mfma_f32_16x16x32_bf16(a[m], b[n], acc[m][n], 0, 0, 0);
    __syncthreads();                         // single wait point per iter
    cur ^= 1;
  }

  // epilogue: bf16 tile through LDS (bias, no relu)
  const int cl0 = wc*64 + (lane & 15);
#pragma unroll
  for (int m=0;m<4;m++)
#pragma unroll
    for (int j=0;j<4;j++){
      int rl = wr*64 + ((lane >> 4) * 4) + m*16 + j;
#pragma unroll
      for (int n=0;n<4;n++){
        int cl = cl0 + n*16;
        smem[rl*128 + cl] = f2b(acc[m][n][j] + bias[bn + cl]);
      }
    }
  __syncthreads();
#pragma unroll
  for (int it=0; it<8; ++it){
    int rl = it*16 + (tid >> 4);
    int cl = (tid & 15) * 8;
    u16x8 vv = *(const u16x8*)(smem + rl*128 + cl);
    *(u16x8*)(Cb + (size_t)z*Cbz + (bm + rl)*(size_t)ldcb + bn + cl) = vv;
  }
}

// ---------------- converters ------------------------------------------------
__global__ void k_copyx_b(const float* __restrict__ x, u16* __restrict__ comb){
  long i = ((long)blockIdx.x*256 + threadIdx.x)*8;   // < NN*IN
  int n = (int)(i >> 8), c = (int)(i & 255);
  float4 v0 = *(const float4*)(x+i);
  float4 v1 = *(const float4*)(x+i+4);
  u16x8 o;
  o[0]=f2b(v0.x); o[1]=f2b(v0.y); o[2]=f2b(v0.z); o[3]=f2b(v0.w);
  o[4]=f2b(v1.x); o[5]=f2b(v1.y); o[6]=f2b(v1.z); o[7]=f2b(v1.w);
  *(u16x8*)(comb + (size_t)n*CD + c) = o;
}

// batched B [K][N] f32 -> Bt [N][K] bf16 (up to 4 matrices). z selects.
__global__ __launch_bounds__(256) void k_transb4(
    const float* __restrict__ B0c, const float* __restrict__ B1c,
    const float* __restrict__ B2c, const float* __restrict__ B3c,
    u16* __restrict__ T0, u16* __restrict__ T1,
    u16* __restrict__ T2, u16* __restrict__ T3, int K, int N){
  __shared__ u16 tile[32][40];
  int z = blockIdx.z;
  const float* B = (z==0)? B0c : (z==1)? B1c : (z==2)? B2c : B3c;
  u16* Bt = (z==0)? T0 : (z==1)? T1 : (z==2)? T2 : T3;
  int n0 = blockIdx.x*32, k0 = blockIdx.y*32;
  int tx = threadIdx.x & 31, ty = threadIdx.x >> 5;   // ty 0..7
#pragma unroll
  for (int i=0;i<4;i++)
    tile[ty+8*i][tx] = f2b(B[(size_t)(k0+ty+8*i)*N + n0+tx]);
  __syncthreads();
#pragma unroll
  for (int i=0;i<4;i++)
    Bt[(size_t)(n0+ty+8*i)*K + k0+tx] = tile[tx][ty+8*i];
}

// ---------------- CSR build -------------------------------------------------
__global__ void k_hist(const int* __restrict__ dst, int* __restrict__ indeg, int E){
  int e = blockIdx.x*256 + threadIdx.x;
  if (e < E) atomicAdd(&indeg[dst[e]], 1);
}

// scan + dinv fused
__global__ __launch_bounds__(1024) void k_scan(const int* __restrict__ indeg,
    int* __restrict__ row_start, int* __restrict__ cursor,
    float* __restrict__ dinv, int Nn)
{
  __shared__ int wsum[16];
  __shared__ int carry_s;
  int t = threadIdx.x, wave = t >> 6, lane = t & 63;
  if (t==0) carry_s = 0;
  __syncthreads();
  for (int base=0; base<Nn; base+=1024) {
    int i = base + t;
    int v = (i<Nn)? indeg[i] : 0;
    int s = v;
#pragma unroll
    for (int o=1;o<64;o<<=1){ int tmp = __shfl_up(s, o); if (lane>=o) s += tmp; }
    if (lane==63) wsum[wave] = s;
    __syncthreads();
    if (wave==0 && lane<16){
      int w = wsum[lane];
#pragma unroll
      for (int o=1;o<16;o<<=1){ int tmp = __shfl_up(w, o); if (lane>=o) w += tmp; }
      wsum[lane] = w;
    }
    __syncthreads();
    int woff = (wave==0)? 0 : wsum[wave-1];
    int incl = s + woff;
    int carry = carry_s;
    if (i<Nn){
      int ex = carry + incl - v;
      row_start[i]=ex; cursor[i]=ex;
      dinv[i] = rsqrtf((float)(v + 1));
    }
    __syncthreads();
    if (t==1023) carry_s = carry + incl;
    __syncthreads();
  }
  if (t==0) row_start[Nn] = carry_s;
}

__global__ void k_scatter(const int* __restrict__ src, const int* __restrict__ dst,
    int* __restrict__ cursor, int* __restrict__ csr_src,
    int* __restrict__ csr_eid, int E){
  int e = blockIdx.x*256 + threadIdx.x;
  if (e < E){
    int d = dst[e];
    int pos = atomicAdd(&cursor[d], 1);
    csr_src[pos] = src[e];
    csr_eid[pos] = e;
  }
}

// ---------------- GCN aggregation (bf16 in, bf16 out), unroll-4 gathers -----
__global__ __launch_bounds__(128) void k_gcn_agg(
    const u16* __restrict__ xw, const int* __restrict__ row_start,
    const int* __restrict__ csr_src, const float* __restrict__ dinv,
    const float* __restrict__ bias, u16* __restrict__ outb)
{
  int d = blockIdx.x, t = threadIdx.x;
  int c0 = t*8;
  float di = dinv[d];
  u16x8 sv = *(const u16x8*)(xw + (size_t)d*HD + c0);
  float acc[8];
#pragma unroll
  for (int i=0;i<8;i++) acc[i] = di*di*b2f(sv[i]);
  int beg = row_start[d], end = row_start[d+1];
  int j = beg;
  for (; j+4 <= end; j += 4){
    int s0=csr_src[j], s1=csr_src[j+1], s2=csr_src[j+2], s3=csr_src[j+3];
    u16x8 r0 = *(const u16x8*)(xw + (size_t)s0*HD + c0);
    u16x8 r1 = *(const u16x8*)(xw + (size_t)s1*HD + c0);
    u16x8 r2 = *(const u16x8*)(xw + (size_t)s2*HD + c0);
    u16x8 r3 = *(const u16x8*)(xw + (size_t)s3*HD + c0);
    float w0=di*dinv[s0], w1=di*dinv[s1], w2=di*dinv[s2], w3=di*dinv[s3];
#pragma unroll
    for (int i=0;i<8;i++){
      acc[i] = fmaf(w0, b2f(r0[i]), acc[i]);
      acc[i] = fmaf(w1, b2f(r1[i]), acc[i]);
      acc[i] = fmaf(w2, b2f(r2[i]), acc[i]);
      acc[i] = fmaf(w3, b2f(r3[i]), acc[i]);
    }
  }
  for (; j<end; ++j){
    int s = csr_src[j];
    float w = di*dinv[s];
    u16x8 rv = *(const u16x8*)(xw + (size_t)s*HD + c0);
#pragma unroll
    for (int i=0;i<8;i++) acc[i] = fmaf(w, b2f(rv[i]), acc[i]);
  }
  float4 bv0 = *(const float4*)(bias + c0);
  float4 bv1 = *(const float4*)(bias + c0 + 4);
  float o[8] = {acc[0]+bv0.x, acc[1]+bv0.y, acc[2]+bv0.z, acc[3]+bv0.w,
                acc[4]+bv1.x, acc[5]+bv1.y, acc[6]+bv1.z, acc[7]+bv1.w};
  u16x8 ob;
#pragma unroll
  for (int i=0;i<8;i++) ob[i]=f2b(o[i]);
  *(u16x8*)(outb + (size_t)d*HD + c0) = ob;
}

// ------- fused GAT: softmax (LDS alpha) + aggregation + residual + LN + ReLU
// block 128 (2 waves), thread t handles cols [t*8, t*8+8), head h0 = t>>5.
// es/ed come as PARTIALS (esp/edp[node*8 + head*2 + parity], written by the
// GAT GEMM epilogue); sum the two 128-col halves on read.
__global__ __launch_bounds__(128) void k_gat_fused(
    const u16* __restrict__ hw, const int* __restrict__ row_start,
    const int* __restrict__ csr_src, const float* __restrict__ esp,
    const float* __restrict__ edp, const float* __restrict__ bias,
    const u16* __restrict__ gcn, const float* __restrict__ g,
    const float* __restrict__ b, u16* __restrict__ out)
{
  __shared__ float4 alph[ACAP];
  __shared__ float xch[8];
  int d = blockIdx.x, t = threadIdx.x, wv = t>>6, lane = t&63;
  int beg = row_start[d], end = row_start[d+1], deg = end-beg;
  float4 e0 = *(const float4*)(edp + (size_t)d*8);
  float4 e1 = *(const float4*)(edp + (size_t)d*8 + 4);
  float4 s0q = *(const float4*)(esp + (size_t)d*8);
  float4 s1q = *(const float4*)(esp + (size_t)d*8 + 4);
  float edv[4] = {e0.x+e0.y, e0.z+e0.w, e1.x+e1.y, e1.z+e1.w};
  float esv[4] = {s0q.x+s0q.y, s0q.z+s0q.w, s1q.x+s1q.y, s1q.z+s1q.w};
  float eself[4], m[4];
#pragma unroll
  for (int h=0;h<4;h++){
    float e = esv[h] + edv[h];
    eself[h] = (e>0.f)? e : NEG_SLOPE*e;
    m[h] = eself[h];
  }
  // pass 1: max over in-edges (128-thread strided)
  for (int j=beg+t; j<end; j+=128){
    int s = csr_src[j];
    float4 q0 = *(const float4*)(esp + (size_t)s*8);
    float4 q1 = *(const float4*)(esp + (size_t)s*8 + 4);
    float qa[4] = {q0.x+q0.y, q0.z+q0.w, q1.x+q1.y, q1.z+q1.w};
#pragma unroll
    for (int h=0;h<4;h++){
      float e = qa[h]+edv[h]; e = (e>0.f)? e : NEG_SLOPE*e;
      m[h] = fmaxf(m[h], e);
    }
  }
#pragma unroll
  for (int h=0;h<4;h++) m[h] = warp_max(m[h]);
  if (lane==0) ((float4*)xch)[wv] = make_float4(m[0],m[1],m[2],m[3]);
  __syncthreads();
  {
    float4 m0 = ((float4*)xch)[0], m1 = ((float4*)xch)[1];
    m[0]=fmaxf(m0.x,m1.x); m[1]=fmaxf(m0.y,m1.y);
    m[2]=fmaxf(m0.z,m1.z); m[3]=fmaxf(m0.w,m1.w);
  }
  __syncthreads();
  // pass 2: sum of exp, cache p in LDS if it fits
  bool fits = (deg <= ACAP);
  float sum[4] = {0.f,0.f,0.f,0.f};
  for (int j=beg+t; j<end; j+=128){
    int s = csr_src[j];
    float4 q0 = *(const float4*)(esp + (size_t)s*8);
    float4 q1 = *(const float4*)(esp + (size_t)s*8 + 4);
    float qa[4] = {q0.x+q0.y, q0.z+q0.w, q1.x+q1.y, q1.z+q1.w}, p[4];
#pragma unroll
    for (int h=0;h<4;h++){
      float e = qa[h]+edv[h]; e = (e>0.f)? e : NEG_SLOPE*e;
      p[h] = expf(e-m[h]); sum[h]+=p[h];
    }
    if (fits) alph[j-beg] = make_float4(p[0],p[1],p[2],p[3]);
  }
#pragma unroll
  for (int h=0;h<4;h++) sum[h]=warp_sum(sum[h]);
  if (lane==0) ((float4*)xch)[wv] = make_float4(sum[0],sum[1],sum[2],sum[3]);
  __syncthreads();
  float rsm[4], swt[4];
  {
    float4 s0=((float4*)xch)[0], s1=((float4*)xch)[1];
    float sa[4] = {s0.x+s1.x, s0.y+s1.y, s0.z+s1.z, s0.w+s1.w};
#pragma unroll
    for (int h=0;h<4;h++){
      float pe = expf(eself[h]-m[h]);
      rsm[h] = 1.f/(sa[h]+pe);
      swt[h] = pe*rsm[h];
    }
  }
  // aggregation (unroll-4 gathers)
  int c0 = t*8, h0 = t>>5;
  u16x8 sv = *(const u16x8*)(hw + (size_t)d*HD + c0);
  float acc[8];
#pragma unroll
  for (int i=0;i<8;i++) acc[i] = swt[h0]*b2f(sv[i]);
  float mh = m[h0], rh = rsm[h0], edh = edv[h0];
  if (fits){
    int j = beg;
    for (; j+4 <= end; j += 4){
      int s0=csr_src[j], s1=csr_src[j+1], s2=csr_src[j+2], s3=csr_src[j+3];
      u16x8 r0 = *(const u16x8*)(hw + (size_t)s0*HD + c0);
      u16x8 r1 = *(const u16x8*)(hw + (size_t)s1*HD + c0);
      u16x8 r2 = *(const u16x8*)(hw + (size_t)s2*HD + c0);
      u16x8 r3 = *(const u16x8*)(hw + (size_t)s3*HD + c0);
      float a0 = ((const float*)&alph[j-beg  ])[h0] * rh;
      float a1 = ((const float*)&alph[j-beg+1])[h0] * rh;
      float a2 = ((const float*)&alph[j-beg+2])[h0] * rh;
      float a3 = ((const float*)&alph[j-beg+3])[h0] * rh;
#pragma unroll
      for (int i=0;i<8;i++){
        acc[i] = fmaf(a0, b2f(r0[i]), acc[i]);
        acc[i] = fmaf(a1, b2f(r1[i]), acc[i]);
        acc[i] = fmaf(a2, b2f(r2[i]), acc[i]);
        acc[i] = fmaf(a3, b2f(r3[i]), acc[i]);
      }
    }
    for (; j<end; ++j){
      int s = csr_src[j];
      float av = ((const float*)&alph[j-beg])[h0] * rh;
      u16x8 rv = *(const u16x8*)(hw + (size_t)s*HD + c0);
#pragma unroll
      for (int i=0;i<8;i++) acc[i] = fmaf(av, b2f(rv[i]), acc[i]);
    }
  } else {
    for (int j=beg; j<end; ++j){
      int s = csr_src[j];
      float qs = esp[(size_t)s*8 + h0*2] + esp[(size_t)s*8 + h0*2 + 1];
      float e = qs + edh; e = (e>0.f)? e : NEG_SLOPE*e;
      float av = expf(e-mh)*rh;
      u16x8 rv = *(const u16x8*)(hw + (size_t)s*HD + c0);
#pragma unroll
      for (int i=0;i<8;i++) acc[i] = fmaf(av, b2f(rv[i]), acc[i]);
    }
  }
  // bias + residual (bf16) + LayerNorm + ReLU
  float4 bv0 = *(const float4*)(bias + c0), bv1 = *(const float4*)(bias + c0 + 4);
  u16x8 gv = *(const u16x8*)(gcn + (size_t)d*HD + c0);
  float ba8[8] = {bv0.x,bv0.y,bv0.z,bv0.w,bv1.x,bv1.y,bv1.z,bv1.w};
  float xv[8];
#pragma unroll
  for (int i=0;i<8;i++) xv[i] = acc[i] + ba8[i] + b2f(gv[i]);
  float ssum=0.f, ssq=0.f;
#pragma unroll
  for (int i=0;i<8;i++){ ssum += xv[i]; ssq = fmaf(xv[i], xv[i], ssq); }
  ssum = warp_sum(ssum); ssq = warp_sum(ssq);
  __syncthreads();   // protect xch reuse
  if (lane==0){ xch[wv]=ssum; xch[2+wv]=ssq; }
  __syncthreads();
  ssum = xch[0]+xch[1]; ssq = xch[2]+xch[3];
  float mean = ssum * (1.f/HD);
  float var  = ssq * (1.f/HD) - mean*mean;
  float rsln = rsqrtf(var + LN_EPS);
  float4 gg0 = *(const float4*)(g + c0), gg1 = *(const float4*)(g + c0 + 4);
  float4 bb0 = *(const float4*)(b + c0), bb1 = *(const float4*)(b + c0 + 4);
  float ga[8] = {gg0.x,gg0.y,gg0.z,gg0.w,gg1.x,gg1.y,gg1.z,gg1.w};
  float ba[8] = {bb0.x,bb0.y,bb0.z,bb0.w,bb1.x,bb1.y,bb1.z,bb1.w};
  u16x8 ob;
#pragma unroll
  for (int i=0;i<8;i++)
    ob[i] = f2b(fmaxf((xv[i]-mean)*rsln*ga[i] + ba[i], 0.f));
  *(u16x8*)(out + (size_t)d*HD + c0) = ob;
}

// ---------------- cosine sims (norms computed inline, no k_norms_b) --------
__global__ __launch_bounds__(256) void k_sims_csr(
    const u16* __restrict__ comb,
    const int* __restrict__ row_start, const int* __restrict__ csr_src,
    const int* __restrict__ csr_eid, float* __restrict__ out, int E)
{
  int d = blockIdx.x;
  int w = threadIdx.x>>6, lane = threadIdx.x&63;
  int g = lane>>4, l = lane&15;          // pair group, lane-in-group
  int beg = row_start[d], end = row_start[d+1];
  if (beg >= end) return;
  const int baseA[4] = {IN, IN+TD,   IN+2*TD, IN+3*TD};   // src: bio, exp, needs, goals
  const int baseB[4] = {IN, IN+2*TD, IN+TD,   IN+3*TD};   // dst: bio, needs, exp, goals
  // dst-side 48 cols for this lane (held across the edge loop)
  const u16* bp = comb + (size_t)d*CD + baseB[g] + l*8;
  float bf[48];
  float nbss = 0.f;
#pragma unroll
  for (int i=0;i<6;i++){
    u16x8 v = *(const u16x8*)(bp + i*128);
#pragma unroll
    for (int k=0;k<8;k++){
      float f = b2f(v[k]);
      bf[i*8+k] = f;
      nbss = fmaf(f, f, nbss);
    }
  }
  nbss += __shfl_xor(nbss,1); nbss += __shfl_xor(nbss,2);
  nbss += __shfl_xor(nbss,4); nbss += __shfl_xor(nbss,8);
  float rnb = 1.f / fmaxf(sqrtf(nbss), COS_EPS);
  for (int j = beg + w; j < end; j += 4){
    int s = csr_src[j];
    const u16* ap = comb + (size_t)s*CD + baseA[g] + l*8;
    float dot = 0.f, ass = 0.f;
#pragma unroll
    for (int i=0;i<6;i++){
      u16x8 v = *(const u16x8*)(ap + i*128);
#pragma unroll
      for (int k=0;k<8;k++){
        float f = b2f(v[k]);
        dot = fmaf(f, bf[i*8+k], dot);
        ass = fmaf(f, f, ass);
      }
    }
    dot += __shfl_xor(dot,1); dot += __shfl_xor(dot,2);
    dot += __shfl_xor(dot,4); dot += __shfl_xor(dot,8);
    ass += __shfl_xor(ass,1); ass += __shfl_xor(ass,2);
    ass += __shfl_xor(ass,4); ass += __shfl_xor(ass,8);
    if (l==0){
      float na = fmaxf(sqrtf(ass), COS_EPS);
      out[(size_t)g*E + csr_eid[j]] = dot * rnb / na;
    }
  }
}

// ---------------- skills / compat ------------------------------------------
__global__ __launch_bounds__(128) void k_skill_mean_b(
    const float* __restrict__ semb, const int* __restrict__ id1,
    const int* __restrict__ id2, u16* __restrict__ comb)
{
  int b = blockIdx.x, c = threadIdx.x;
  float s1=0.f, s2=0.f;
  for (int k=0;k<KSK;k++){
    s1 += semb[(size_t)id1[b*KSK+k]*SDIM + c];
    s2 += semb[(size_t)id2[b*KSK+k]*SDIM + c];
  }
  comb[(size_t)b*256 + c]       = f2b(s1*(1.f/KSK));
  comb[(size_t)b*256 + 128 + c] = f2b(s2*(1.f/KSK));
}

__global__ __launch_bounds__(256) void k_compat(
    const float* __restrict__ hidden, const float* __restrict__ w2,
    const float* __restrict__ b2, float* __restrict__ out)
{
  __shared__ float red[4];
  int bi = blockIdx.x, t = threadIdx.x;
  float s = 0.f;
  for (int c=t;c<HD;c+=256) s = fmaf(hidden[(size_t)bi*HD+c], w2[c], s);
  s = warp_sum(s);
  if ((t&63)==0) red[t>>6] = s;
  __syncthreads();
  if (t==0){
    float tot = red[0]+red[1]+red[2]+red[3] + b2[0];
    out[bi] = 1.f/(1.f+expf(-tot));
  }
}

// ---------------------------------------------------------------------------
extern "C" void kernel_launch(void* const* d_in, const int* in_sizes, int n_in,
                              void* d_out, int out_size, void* d_ws, size_t ws_size,
                              hipStream_t stream)
{
  const float* x         = (const float*)d_in[0];
  const int*   eidx      = (const int*)d_in[1];
  const int*   dom_ids   = (const int*)d_in[2];
  const int*   sk1       = (const int*)d_in[3];
  const int*   sk2       = (const int*)d_in[4];
  const float* bio_emb   = (const float*)d_in[5];
  const float* bio_w     = (const float*)d_in[6];
  const float* bio_b     = (const float*)d_in[7];
  const float* exp_emb   = (const float*)d_in[8];
  const float* exp_w     = (const float*)d_in[9];
  const float* exp_b     = (const float*)d_in[10];
  const float* needs_emb = (const float*)d_in[11];
  const float* needs_w   = (const float*)d_in[12];
  const float* needs_b   = (const float*)d_in[13];
  const float* goals_emb = (const float*)d_in[14];
  const float* goals_w   = (const float*)d_in[15];
  const float* goals_b   = (const float*)d_in[16];
  const float* gcn_w0 = (const float*)d_in[17];
  const float* gcn_b0 = (const float*)d_in[18];
  const float* gat_w0 = (const float*)d_in[19];
  const float* gat_as0= (const float*)d_in[20];
  const float* gat_ad0= (const float*)d_in[21];
  const float* gat_b0 = (const float*)d_in[22];
  const float* ln_g0  = (const float*)d_in[23];
  const float* ln_b0  = (const float*)d_in[24];
  const float* gcn_w1 = (const float*)d_in[25];
  const float* gcn_b1 = (const float*)d_in[26];
  const float* gat_w1 = (const float*)d_in[27];
  const float* gat_as1= (const float*)d_in[28];
  const float* gat_ad1= (const float*)d_in[29];
  const float* gat_b1 = (const float*)d_in[30];
  const float* ln_g1  = (const float*)d_in[31];
  const float* ln_b1  = (const float*)d_in[32];
  const float* dom_emb= (const float*)d_in[33];
  const float* dom_w  = (const float*)d_in[34];
  const float* dom_b  = (const float*)d_in[35];
  const float* skill_emb = (const float*)d_in[36];
  const float* c_w1   = (const float*)d_in[37];
  const float* c_b1   = (const float*)d_in[38];
  const float* c_w2   = (const float*)d_in[39];
  const float* c_b2   = (const float*)d_in[40];

  const int E   = in_sizes[1] / 2;
  const int Bsz = in_sizes[3] / KSK;
  const int* srcp = eidx;
  const int* dstp = eidx + E;

  // ---- workspace bump allocator (256B aligned) ----
  char* wsp = (char*)d_ws;
  size_t off = 0;
  auto alloc = [&](size_t bytes)->void*{
    void* p = wsp + off;
    off += (bytes + 255) & ~(size_t)255;
    return p;
  };
  u16*   combined_b = (u16*)alloc((size_t)MP*CD*2);  // 67.3 MB (dead after GCN0 gemm)
  u16*   P0b  = (u16*) alloc((size_t)MP*HD*2);       // xw    (bf16)
  u16*   P1b  = (u16*) alloc((size_t)MP*HD*2);       // x_gcn (bf16: GAT A + LN residual)
  u16*   Rh   = (u16*) alloc((size_t)MP*HD*2);       // layer output bf16
  u16*   wt_bio   = (u16*)alloc((size_t)TD*TD*2);
  u16*   wt_exp   = (u16*)alloc((size_t)TD*TD*2);
  u16*   wt_needs = (u16*)alloc((size_t)TD*TD*2);
  u16*   wt_goals = (u16*)alloc((size_t)TD*TD*2);
  u16*   w_gcn0t  = (u16*)alloc((size_t)HD*CD*2);
  u16*   w_gat0t  = (u16*)alloc((size_t)HD*HD*2);
  u16*   w_gcn1t  = (u16*)alloc((size_t)HD*HD*2);
  u16*   w_gat1t  = (u16*)alloc((size_t)HD*HD*2);
  u16*   w_domt   = (u16*)alloc((size_t)HD*HD*2);
  u16*   w_c1t    = (u16*)alloc((size_t)HD*2*SDIM*2);
  u16*   comb_b   = (u16*)alloc((size_t)Bsz*2*SDIM*2);
  float* hidden   = (float*)alloc((size_t)Bsz*HD*4);
  float* esp     = (float*)alloc((size_t)NN*8*4);    // GAT logit partials (s)
  float* edp     = (float*)alloc((size_t)NN*8*4);    // GAT logit partials (d)
  float* dinv    = (float*)alloc((size_t)NN*4);
  int*   indeg   = (int*)  alloc((size_t)NN*4);
  int*   row_st  = (int*)  alloc((size_t)(NN+1)*4);
  int*   cursor  = (int*)  alloc((size_t)NN*4);
  int*   csr_src = (int*)  alloc((size_t)E*4);
  int*   csr_eid = (int*)  alloc((size_t)E*4);

  // overlay: hw (bf16 GAT gemm output) reuses combined_b once it's dead
  u16* Rhwb = combined_b;

  float* out0       = (float*)d_out;                  // domain_embeddings [NN,HD]
  float* out_compat = out0 + (size_t)NN*HD;           // [Bsz]
  float* out_sims   = out_compat + Bsz;               // 4 x [E] contiguous

  dim3 blk(256);

  // 0. CSR by dst
  hipMemsetAsync(indeg, 0, (size_t)NN*sizeof(int), stream);
  k_hist<<<dim3((E+255)/256), blk, 0, stream>>>(dstp, indeg, E);
  k_scan<<<dim3(1), dim3(1024), 0, stream>>>(indeg, row_st, cursor, dinv, NN);
  k_scatter<<<dim3((E+255)/256), blk, 0, stream>>>(srcp, dstp, cursor, csr_src, csr_eid, E);

  // 1. weight transposes -> bf16 [N][K] (batched)
  k_transb4<<<dim3(TD/32, TD/32, 4), blk, 0, stream>>>(
      bio_w, exp_w, needs_w, goals_w, wt_bio, wt_exp, wt_needs, wt_goals, TD, TD);
  k_transb4<<<dim3(HD/32, HD/32, 4), blk, 0, stream>>>(
      gat_w0, gcn_w1, gat_w1, dom_w, w_gat0t, w_gcn1t, w_gat1t, w_domt, HD, HD);
  k_transb4<<<dim3(HD/32, CD/32, 1), blk, 0, stream>>>(
      gcn_w0, gcn_w0, gcn_w0, gcn_w0, w_gcn0t, w_gcn0t, w_gcn0t, w_gcn0t, CD, HD);
  k_transb4<<<dim3(HD/32, (2*SDIM)/32, 1), blk, 0, stream>>>(
      c_w1, c_w1, c_w1, c_w1, w_c1t, w_c1t, w_c1t, w_c1t, 2*SDIM, HD);

  // 2. combined_b = [x | bio_f | exp_f | needs_f | goals_f] (bf16)
  //    text GEMM reads the f32 embeddings DIRECTLY (no f2b pass, no Aact)
  k_copyx_b<<<dim3((NN*IN)/8/256), blk, 0, stream>>>(x, combined_b);
  k_gemm_text<<<dim3(TD/128, MP/128, 4), blk, 0, stream>>>(
      bio_emb, exp_emb, needs_emb, goals_emb,
      wt_bio, wt_exp, wt_needs, wt_goals,
      bio_b, exp_b, needs_b, goals_b,
      combined_b + IN, CD, (long)TD, NN, TD);

  // 3. cosine sims (dst-stationary, CSR order; norms inline)
  k_sims_csr<<<dim3(NN), blk, 0, stream>>>(combined_b, row_st, csr_src,
                                           csr_eid, out_sims, E);

  // 4. skill / compat path
  k_skill_mean_b<<<dim3(Bsz), dim3(128), 0, stream>>>(skill_emb, sk1, sk2, comb_b);
  k_gemm_bf16<<<dim3(HD/128, Bsz/128, 1), blk, 0, stream>>>(
      comb_b, 0, w_c1t, w_c1t, w_c1t, w_c1t, c_b1, c_b1, c_b1, c_b1,
      hidden, HD, nullptr, 0, 0, nullptr, nullptr, Bsz, 2*SDIM, 1,
      nullptr, nullptr, nullptr, nullptr);
  k_compat<<<dim3(Bsz), blk, 0, stream>>>(hidden, c_w2, c_b2, out_compat);

  dim3 g_h(HD/128, MP/128, 1);

  // 5. layer 0 (es/ed partials fused into the GAT gemm epilogue, non-atomic)
  k_gemm_bf16<<<g_h, blk, 0, stream>>>(
      combined_b, 0, w_gcn0t, w_gcn0t, w_gcn0t, w_gcn0t,
      nullptr, nullptr, nullptr, nullptr,
      nullptr, 0, P0b, HD, 0, nullptr, nullptr, NN, CD, 0,
      nullptr, nullptr, nullptr, nullptr);
  k_gcn_agg<<<dim3(NN), dim3(128), 0, stream>>>(P0b, row_st, csr_src, dinv, gcn_b0, P1b);
  k_gemm_bf16<<<g_h, blk, 0, stream>>>(
      P1b, 0, w_gat0t, w_gat0t, w_gat0t, w_gat0t,
      nullptr, nullptr, nullptr, nullptr,
      nullptr, 0, Rhwb, HD, 0, nullptr, nullptr, NN, HD, 0,
      gat_as0, gat_ad0, esp, edp);
  k_gat_fused<<<dim3(NN), dim3(128), 0, stream>>>(Rhwb, row_st, csr_src, esp, edp,
                                                  gat_b0, P1b, ln_g0, ln_b0, Rh);

  // 6. layer 1
  k_gemm_bf16<<<g_h, blk, 0, stream>>>(
      Rh, 0, w_gcn1t, w_gcn1t, w_gcn1t, w_gcn1t,
      nullptr, nullptr, nullptr, nullptr,
      nullptr, 0, P0b, HD, 0, nullptr, nullptr, NN, HD, 0,
      nullptr, nullptr, nullptr, nullptr);
  k_gcn_agg<<<dim3(NN), dim3(128), 0, stream>>>(P0b, row_st, csr_src, dinv, gcn_b1, P1b);
  k_gemm_bf16<<<g_h, blk, 0, stream>>>(
      P1b, 0, w_gat1t, w_gat1t, w_gat1t, w_gat1t,
      nullptr, nullptr, nullptr, nullptr,
      nullptr, 0, Rhwb, HD, 0, nullptr, nullptr, NN, HD, 0,
      gat_as1, gat_ad1, esp, edp);
  k_gat_fused<<<dim3(NN), dim3(128), 0, stream>>>(Rhwb, row_st, csr_src, esp, edp,
                                                  gat_b1, P1b, ln_g1, ln_b1, Rh);

  // 7. domain embeddings (dom_emb gather fused into epilogue)
  k_gemm_bf16<<<g_h, blk, 0, stream>>>(
      Rh, 0, w_domt, w_domt, w_domt, w_domt,
      dom_b, dom_b, dom_b, dom_b,
      out0, HD, nullptr, 0, 0, dom_emb, dom_ids, NN, HD, 0,
      nullptr, nullptr, nullptr, nullptr);
}

// Round 8
// 632.228 us; speedup vs baseline: 1.1896x; 1.1896x over previous
//
#include <hip/hip_runtime.h>
#include <math.h>

typedef unsigned short u16;
typedef unsigned short u16x4 __attribute__((ext_vector_type(4)));
typedef unsigned short u16x8 __attribute__((ext_vector_type(8)));
typedef short s16x8 __attribute__((ext_vector_type(8)));
typedef float f32x4 __attribute__((ext_vector_type(4)));

constexpr int NN   = 10000;   // nodes
constexpr int MP   = 10112;   // nodes padded to multiple of 128
constexpr int IN   = 256;
constexpr int TD   = 768;
constexpr int CD   = 3328;    // IN + 4*TD
constexpr int HD   = 1024;
constexpr int HCH  = 256;     // HD/4 heads
constexpr int SDIM = 128;
constexpr int KSK  = 20;
constexpr int ACAP = 256;     // LDS alpha capacity (edges) in fused GAT
constexpr float LN_EPS = 1e-5f;
constexpr float COS_EPS = 1e-8f;
constexpr float NEG_SLOPE = 0.2f;

__device__ __forceinline__ float warp_sum(float v){
#pragma unroll
  for (int o=1;o<64;o<<=1) v += __shfl_xor(v,o);
  return v;
}
__device__ __forceinline__ float warp_max(float v){
#pragma unroll
  for (int o=1;o<64;o<<=1) v = fmaxf(v, __shfl_xor(v,o));
  return v;
}
__device__ __forceinline__ u16 f2b(float f){
  unsigned u = __float_as_uint(f);
  return (u16)((u + 0x7fffu + ((u>>16)&1u)) >> 16);
}
__device__ __forceinline__ float b2f(u16 b){ return __uint_as_float(((unsigned)b)<<16); }

#define GLDS(g, l) __builtin_amdgcn_global_load_lds( \
    (const __attribute__((address_space(1))) void*)(g), \
    (__attribute__((address_space(3))) void*)(l), 16, 0, 0)

// ---------------- bf16 MFMA GEMM: C[M,N] = A[Mpad,K](bf16) @ Bt[N,K]^T ------
// grid (N/128, Mpad/128, Z), block 256 (4 waves, 2x2, 64x64 each). K%32==0.
// 2-phase double-buffered LDS prefetch (proven BK=32, 32KB LDS) + XCD swizzle.
// Epilogue stages C through LDS for coalesced 16B stores.
// NOTE (R2+R7 post-mortems): do NOT fuse ANYTHING into this epilogue — both
// atomic (R2: +150us) and non-atomic partial-store (R7: +120us) es/ed fusions
// regressed ~10x the kernel they deleted. Epilogue is modification-intolerant.
__global__ __launch_bounds__(256) void k_gemm_bf16(
    const u16* __restrict__ A, long Az,
    const u16* __restrict__ B0c, const u16* __restrict__ B1c,
    const u16* __restrict__ B2c, const u16* __restrict__ B3c,
    const float* __restrict__ bias0, const float* __restrict__ bias1,
    const float* __restrict__ bias2, const float* __restrict__ bias3,
    float* __restrict__ Cf, int ldcf,
    u16* __restrict__ Cb, int ldcb, long Cbz,
    const float* __restrict__ demb, const int* __restrict__ dids,
    int M, int K, int relu)
{
  __shared__ __align__(16) u16 smem[16384];   // 32KB: staging OR C-tile
  // staging partition: A buf0 @0, A buf1 @4096, B buf0 @8192, B buf1 @12288
  const int z = blockIdx.z;
  const u16* Bt = (z==0)? B0c : (z==1)? B1c : (z==2)? B2c : B3c;
  const float* bias = (z==0)? bias0 : (z==1)? bias1 : (z==2)? bias2 : bias3;
  const u16* Ab = A + (size_t)z * (size_t)Az;

  const int tid = threadIdx.x;
  const int wave = tid >> 6, lane = tid & 63;
  const int wr = wave >> 1, wc = wave & 1;

  // bijective XCD swizzle (m204)
  const int nwg  = gridDim.x * gridDim.y;
  const int orig = blockIdx.y * gridDim.x + blockIdx.x;
  const int q = nwg >> 3, r = nwg & 7;
  const int xcd = orig & 7, loc = orig >> 3;
  const int wg = (xcd < r ? xcd*(q+1) : r*(q+1) + (xcd-r)*q) + loc;
  const int bx = wg % gridDim.x, byy = wg / gridDim.x;
  const size_t bm = (size_t)byy * 128;
  const size_t bn = (size_t)bx * 128;

  f32x4 acc[4][4];
#pragma unroll
  for (int m=0;m<4;m++)
#pragma unroll
    for (int n=0;n<4;n++) acc[m][n] = f32x4{0.f,0.f,0.f,0.f};

  const int srow = tid >> 2;
  const int scol = (tid & 3) * 8;
  const u16* ga0 = Ab + (bm + srow) * (size_t)K + scol;
  const u16* ga1 = ga0 + (size_t)64 * K;
  const u16* gb0 = Bt + (bn + srow) * (size_t)K + scol;
  const u16* gb1 = gb0 + (size_t)64 * K;

  auto stage = [&](int buf, int k0){
    GLDS(ga0 + k0, smem + buf*4096 + wave*512);
    GLDS(ga1 + k0, smem + buf*4096 + 2048 + wave*512);
    GLDS(gb0 + k0, smem + 8192 + buf*4096 + wave*512);
    GLDS(gb1 + k0, smem + 8192 + buf*4096 + 2048 + wave*512);
  };

  const int ar = wr*64 + (lane & 15);     // A row within tile
  const int br = wc*64 + (lane & 15);     // B col within tile
  const int kg = (lane >> 4) * 8;         // k group

  const int nt = K >> 5;
  stage(0, 0);
  __syncthreads();                         // drains vmcnt(0)
  int cur = 0;
  for (int t = 0; t < nt; ++t){
    if (t+1 < nt) stage(cur^1, (t+1)*32);  // async prefetch overlaps MFMAs
    s16x8 a[4], b[4];
#pragma unroll
    for (int m=0;m<4;m++) a[m] = *(const s16x8*)(smem + cur*4096 + (ar + m*16)*32 + kg);
#pragma unroll
    for (int n=0;n<4;n++) b[n] = *(const s16x8*)(smem + 8192 + cur*4096 + (br + n*16)*32 + kg);
#pragma unroll
    for (int m=0;m<4;m++)
#pragma unroll
      for (int n=0;n<4;n++)
        acc[m][n] = __builtin_amdgcn_mfma_f32_16x16x32_bf16(a[m], b[n], acc[m][n], 0, 0, 0);
    __syncthreads();                       // one barrier/iter, drains prefetch
    cur ^= 1;
  }
  // after the loop's final barrier, smem is dead -> reuse for the C tile

  const int cl0 = wc*64 + (lane & 15);     // local col base
  if (Cb){
    // bf16 path: full [128][128] tile in LDS, then 8 coalesced 16B stores/thread
#pragma unroll
    for (int m=0;m<4;m++)
#pragma unroll
      for (int j=0;j<4;j++){
        int rl = wr*64 + ((lane >> 4) * 4) + m*16 + j;
#pragma unroll
        for (int n=0;n<4;n++){
          int cl = cl0 + n*16;
          float v = acc[m][n][j];
          if (bias) v += bias[bn + cl];
          if (relu) v = fmaxf(v, 0.f);
          smem[rl*128 + cl] = f2b(v);
        }
      }
    __syncthreads();
#pragma unroll
    for (int it=0; it<8; ++it){
      int rl = it*16 + (tid >> 4);
      int cl = (tid & 15) * 8;
      u16x8 vv = *(const u16x8*)(smem + rl*128 + cl);
      *(u16x8*)(Cb + (size_t)z*Cbz + (bm + rl)*(size_t)ldcb + bn + cl) = vv;
    }
  } else if (Cf){
    // f32 path: two [64][128] passes through LDS, 16B f32x4 stores
    float* ctf = (float*)smem;
#pragma unroll
    for (int p=0;p<2;p++){
      if (wr == p){
#pragma unroll
        for (int m=0;m<4;m++)
#pragma unroll
          for (int j=0;j<4;j++){
            int rl = ((lane >> 4) * 4) + m*16 + j;        // 0..63 in half
            int rg = (int)bm + p*64 + rl;
            const float* dbase = (demb && rg < M) ? demb + (size_t)dids[rg]*HD : nullptr;
#pragma unroll
            for (int n=0;n<4;n++){
              int cl = cl0 + n*16;
              float v = acc[m][n][j];
              if (bias) v += bias[bn + cl];
              if (dbase) v += dbase[bn + cl];
              if (relu) v = fmaxf(v, 0.f);
              ctf[rl*128 + cl] = v;
            }
          }
      }
      __syncthreads();
#pragma unroll
      for (int it=0; it<8; ++it){
        int rl = it*8 + (tid >> 5);
        int cl = (tid & 31) * 4;
        int rg = (int)bm + p*64 + rl;
        if (rg < M){
          float4 vv = *(const float4*)(ctf + rl*128 + cl);
          *(float4*)(Cf + (size_t)rg*ldcf + bn + cl) = vv;
        }
      }
      __syncthreads();
    }
  }
}

// ------- text GEMM: A is f32 (raw embeddings), converted to bf16 in-kernel --
// C[M,TD](bf16, z-offset cols) = f2b(Af32[M,K]) @ Bt[TD,K]^T + bias.
// One register set; wrA at iteration top (consumes regs drained by the prev
// barrier), reload immediately after. Saves the k_f2b8x4 pass + 62MB Aact.
// (R6: order-neutral vs R4 — structure-bound at ~128us; do not re-grind.)
__global__ __launch_bounds__(256) void k_gemm_text(
    const float* __restrict__ A0, const float* __restrict__ A1,
    const float* __restrict__ A2, const float* __restrict__ A3,
    const u16* __restrict__ B0c, const u16* __restrict__ B1c,
    const u16* __restrict__ B2c, const u16* __restrict__ B3c,
    const float* __restrict__ bias0, const float* __restrict__ bias1,
    const float* __restrict__ bias2, const float* __restrict__ bias3,
    u16* __restrict__ Cb, int ldcb, long Cbz, int M, int K)
{
  __shared__ __align__(16) u16 smem[16384];   // 32KB: staging OR C-tile
  const int z = blockIdx.z;
  const float* Af = (z==0)? A0 : (z==1)? A1 : (z==2)? A2 : A3;
  const u16* Bt = (z==0)? B0c : (z==1)? B1c : (z==2)? B2c : B3c;
  const float* bias = (z==0)? bias0 : (z==1)? bias1 : (z==2)? bias2 : bias3;

  const int tid = threadIdx.x;
  const int wave = tid >> 6, lane = tid & 63;
  const int wr = wave >> 1, wc = wave & 1;

  // bijective XCD swizzle (m204)
  const int nwg  = gridDim.x * gridDim.y;
  const int orig = blockIdx.y * gridDim.x + blockIdx.x;
  const int q = nwg >> 3, r = nwg & 7;
  const int xcd = orig & 7, loc = orig >> 3;
  const int wg = (xcd < r ? xcd*(q+1) : r*(q+1) + (xcd-r)*q) + loc;
  const int bx = wg % gridDim.x, byy = wg / gridDim.x;
  const size_t bm = (size_t)byy * 128;
  const size_t bn = (size_t)bx * 128;

  f32x4 acc[4][4];
#pragma unroll
  for (int m=0;m<4;m++)
#pragma unroll
    for (int n=0;n<4;n++) acc[m][n] = f32x4{0.f,0.f,0.f,0.f};

  // B staging via GLDS (unchanged layout: B buf0 @8192, buf1 @12288 u16)
  const int srow = tid >> 2;
  const int scol = (tid & 3) * 8;
  const u16* gb0 = Bt + (bn + srow) * (size_t)K + scol;
  const u16* gb1 = gb0 + (size_t)64 * K;
  auto stageB = [&](int buf, int k0){
    GLDS(gb0 + k0, smem + 8192 + buf*4096 + wave*512);
    GLDS(gb1 + k0, smem + 8192 + buf*4096 + 2048 + wave*512);
  };

  // A f32 reg staging: thread -> row r0l (0..127), col half c0l (0 or 16)
  const int r0l = tid >> 1;
  const int c0l = (tid & 1) * 16;
  int rr = (int)bm + r0l; if (rr > M-1) rr = M-1;   // pad rows clamp (never read)
  const float* ga = Af + (size_t)rr * (size_t)K + c0l;

  float4 av0, av1, av2, av3;                 // ONE register set
  auto ldA = [&](int k0){
    av0 = *(const float4*)(ga + k0);
    av1 = *(const float4*)(ga + k0 + 4);
    av2 = *(const float4*)(ga + k0 + 8);
    av3 = *(const float4*)(ga + k0 + 12);
  };
  auto wrA = [&](int buf){
    u16x8 o0, o1;
    o0[0]=f2b(av0.x); o0[1]=f2b(av0.y); o0[2]=f2b(av0.z); o0[3]=f2b(av0.w);
    o0[4]=f2b(av1.x); o0[5]=f2b(av1.y); o0[6]=f2b(av1.z); o0[7]=f2b(av1.w);
    o1[0]=f2b(av2.x); o1[1]=f2b(av2.y); o1[2]=f2b(av2.z); o1[3]=f2b(av2.w);
    o1[4]=f2b(av3.x); o1[5]=f2b(av3.y); o1[6]=f2b(av3.z); o1[7]=f2b(av3.w);
    *(u16x8*)(smem + buf*4096 + r0l*32 + c0l)     = o0;
    *(u16x8*)(smem + buf*4096 + r0l*32 + c0l + 8) = o1;
  };

  const int ar = wr*64 + (lane & 15);
  const int br = wc*64 + (lane & 15);
  const int kg = (lane >> 4) * 8;

  const int nt = K >> 5;
  // prologue: tile0 -> buf0 (regs consumed immediately), then tile1 -> regs
  ldA(0); stageB(0, 0); wrA(0);
  if (nt > 1) ldA(32);
  __syncthreads();                           // drains everything (vmcnt(0))
  int cur = 0;
  for (int t = 0; t < nt; ++t){
    if (t+1 < nt){
      wrA(cur^1);                            // regs drained by PREV barrier: no wait
      if (t+2 < nt) ldA((t+2)*32);           // reuse the set; full-iter slack
      stageB(cur^1, (t+1)*32);
    }
    s16x8 a[4], b[4];
#pragma unroll
    for (int m=0;m<4;m++) a[m] = *(const s16x8*)(smem + cur*4096 + (ar + m*16)*32 + kg);
#pragma unroll
    for (int n=0;n<4;n++) b[n] = *(const s16x8*)(smem + 8192 + cur*4096 + (br + n*16)*32 + kg);
#pragma unroll
    for (int m=0;m<4;m++)
#pragma unroll
      for (int n=0;n<4;n++)
        acc[m][n] = __builtin_amdgcn_mfma_f32_16x16x32_bf16(a[m], b[n], acc[m][n], 0, 0, 0);
    __syncthreads();                         // single wait point per iter
    cur ^= 1;
  }

  // epilogue: bf16 tile through LDS (bias, no relu)
  const int cl0 = wc*64 + (lane & 15);
#pragma unroll
  for (int m=0;m<4;m++)
#pragma unroll
    for (int j=0;j<4;j++){
      int rl = wr*64 + ((lane >> 4) * 4) + m*16 + j;
#pragma unroll
      for (int n=0;n<4;n++){
        int cl = cl0 + n*16;
        smem[rl*128 + cl] = f2b(acc[m][n][j] + bias[bn + cl]);
      }
    }
  __syncthreads();
#pragma unroll
  for (int it=0; it<8; ++it){
    int rl = it*16 + (tid >> 4);
    int cl = (tid & 15) * 8;
    u16x8 vv = *(const u16x8*)(smem + rl*128 + cl);
    *(u16x8*)(Cb + (size_t)z*Cbz + (bm + rl)*(size_t)ldcb + bn + cl) = vv;
  }
}

// ---------------- converters ------------------------------------------------
__global__ void k_copyx_b(const float* __restrict__ x, u16* __restrict__ comb){
  long i = ((long)blockIdx.x*256 + threadIdx.x)*8;   // < NN*IN
  int n = (int)(i >> 8), c = (int)(i & 255);
  float4 v0 = *(const float4*)(x+i);
  float4 v1 = *(const float4*)(x+i+4);
  u16x8 o;
  o[0]=f2b(v0.x); o[1]=f2b(v0.y); o[2]=f2b(v0.z); o[3]=f2b(v0.w);
  o[4]=f2b(v1.x); o[5]=f2b(v1.y); o[6]=f2b(v1.z); o[7]=f2b(v1.w);
  *(u16x8*)(comb + (size_t)n*CD + c) = o;
}

// batched B [K][N] f32 -> Bt [N][K] bf16 (up to 4 matrices). z selects.
__global__ __launch_bounds__(256) void k_transb4(
    const float* __restrict__ B0c, const float* __restrict__ B1c,
    const float* __restrict__ B2c, const float* __restrict__ B3c,
    u16* __restrict__ T0, u16* __restrict__ T1,
    u16* __restrict__ T2, u16* __restrict__ T3, int K, int N){
  __shared__ u16 tile[32][40];
  int z = blockIdx.z;
  const float* B = (z==0)? B0c : (z==1)? B1c : (z==2)? B2c : B3c;
  u16* Bt = (z==0)? T0 : (z==1)? T1 : (z==2)? T2 : T3;
  int n0 = blockIdx.x*32, k0 = blockIdx.y*32;
  int tx = threadIdx.x & 31, ty = threadIdx.x >> 5;   // ty 0..7
#pragma unroll
  for (int i=0;i<4;i++)
    tile[ty+8*i][tx] = f2b(B[(size_t)(k0+ty+8*i)*N + n0+tx]);
  __syncthreads();
#pragma unroll
  for (int i=0;i<4;i++)
    Bt[(size_t)(n0+ty+8*i)*K + k0+tx] = tile[tx][ty+8*i];
}

// ---------------- CSR build -------------------------------------------------
__global__ void k_hist(const int* __restrict__ dst, int* __restrict__ indeg, int E){
  int e = blockIdx.x*256 + threadIdx.x;
  if (e < E) atomicAdd(&indeg[dst[e]], 1);
}

// scan + dinv fused
__global__ __launch_bounds__(1024) void k_scan(const int* __restrict__ indeg,
    int* __restrict__ row_start, int* __restrict__ cursor,
    float* __restrict__ dinv, int Nn)
{
  __shared__ int wsum[16];
  __shared__ int carry_s;
  int t = threadIdx.x, wave = t >> 6, lane = t & 63;
  if (t==0) carry_s = 0;
  __syncthreads();
  for (int base=0; base<Nn; base+=1024) {
    int i = base + t;
    int v = (i<Nn)? indeg[i] : 0;
    int s = v;
#pragma unroll
    for (int o=1;o<64;o<<=1){ int tmp = __shfl_up(s, o); if (lane>=o) s += tmp; }
    if (lane==63) wsum[wave] = s;
    __syncthreads();
    if (wave==0 && lane<16){
      int w = wsum[lane];
#pragma unroll
      for (int o=1;o<16;o<<=1){ int tmp = __shfl_up(w, o); if (lane>=o) w += tmp; }
      wsum[lane] = w;
    }
    __syncthreads();
    int woff = (wave==0)? 0 : wsum[wave-1];
    int incl = s + woff;
    int carry = carry_s;
    if (i<Nn){
      int ex = carry + incl - v;
      row_start[i]=ex; cursor[i]=ex;
      dinv[i] = rsqrtf((float)(v + 1));
    }
    __syncthreads();
    if (t==1023) carry_s = carry + incl;
    __syncthreads();
  }
  if (t==0) row_start[Nn] = carry_s;
}

__global__ void k_scatter(const int* __restrict__ src, const int* __restrict__ dst,
    int* __restrict__ cursor, int* __restrict__ csr_src,
    int* __restrict__ csr_eid, int E){
  int e = blockIdx.x*256 + threadIdx.x;
  if (e < E){
    int d = dst[e];
    int pos = atomicAdd(&cursor[d], 1);
    csr_src[pos] = src[e];
    csr_eid[pos] = e;
  }
}

// ---------------- GCN aggregation (bf16 in, bf16 out), unroll-4 gathers -----
__global__ __launch_bounds__(128) void k_gcn_agg(
    const u16* __restrict__ xw, const int* __restrict__ row_start,
    const int* __restrict__ csr_src, const float* __restrict__ dinv,
    const float* __restrict__ bias, u16* __restrict__ outb)
{
  int d = blockIdx.x, t = threadIdx.x;
  int c0 = t*8;
  float di = dinv[d];
  u16x8 sv = *(const u16x8*)(xw + (size_t)d*HD + c0);
  float acc[8];
#pragma unroll
  for (int i=0;i<8;i++) acc[i] = di*di*b2f(sv[i]);
  int beg = row_start[d], end = row_start[d+1];
  int j = beg;
  for (; j+4 <= end; j += 4){
    int s0=csr_src[j], s1=csr_src[j+1], s2=csr_src[j+2], s3=csr_src[j+3];
    u16x8 r0 = *(const u16x8*)(xw + (size_t)s0*HD + c0);
    u16x8 r1 = *(const u16x8*)(xw + (size_t)s1*HD + c0);
    u16x8 r2 = *(const u16x8*)(xw + (size_t)s2*HD + c0);
    u16x8 r3 = *(const u16x8*)(xw + (size_t)s3*HD + c0);
    float w0=di*dinv[s0], w1=di*dinv[s1], w2=di*dinv[s2], w3=di*dinv[s3];
#pragma unroll
    for (int i=0;i<8;i++){
      acc[i] = fmaf(w0, b2f(r0[i]), acc[i]);
      acc[i] = fmaf(w1, b2f(r1[i]), acc[i]);
      acc[i] = fmaf(w2, b2f(r2[i]), acc[i]);
      acc[i] = fmaf(w3, b2f(r3[i]), acc[i]);
    }
  }
  for (; j<end; ++j){
    int s = csr_src[j];
    float w = di*dinv[s];
    u16x8 rv = *(const u16x8*)(xw + (size_t)s*HD + c0);
#pragma unroll
    for (int i=0;i<8;i++) acc[i] = fmaf(w, b2f(rv[i]), acc[i]);
  }
  float4 bv0 = *(const float4*)(bias + c0);
  float4 bv1 = *(const float4*)(bias + c0 + 4);
  float o[8] = {acc[0]+bv0.x, acc[1]+bv0.y, acc[2]+bv0.z, acc[3]+bv0.w,
                acc[4]+bv1.x, acc[5]+bv1.y, acc[6]+bv1.z, acc[7]+bv1.w};
  u16x8 ob;
#pragma unroll
  for (int i=0;i<8;i++) ob[i]=f2b(o[i]);
  *(u16x8*)(outb + (size_t)d*HD + c0) = ob;
}

// ---------------- GAT: per-node attn logits --------------------------------
__global__ __launch_bounds__(256) void k_es_ed(
    const u16* __restrict__ hw, const float* __restrict__ a_s,
    const float* __restrict__ a_d, float* __restrict__ es, float* __restrict__ ed)
{
  int n = blockIdx.x; int wv = threadIdx.x >> 6; int lane = threadIdx.x & 63;
  u16x4 v  = *(const u16x4*)(hw + (size_t)n*HD + wv*HCH + lane*4);
  float4 as = *(const float4*)(a_s + wv*HCH + lane*4);
  float4 ad = *(const float4*)(a_d + wv*HCH + lane*4);
  float f0=b2f(v[0]), f1=b2f(v[1]), f2v=b2f(v[2]), f3=b2f(v[3]);
  float ss = f0*as.x + f1*as.y + f2v*as.z + f3*as.w;
  float sd = f0*ad.x + f1*ad.y + f2v*ad.z + f3*ad.w;
  ss = warp_sum(ss); sd = warp_sum(sd);
  if (lane==0){ es[n*4+wv]=ss; ed[n*4+wv]=sd; }
}

// ------- fused GAT: softmax (LDS alpha) + aggregation + residual + LN + ReLU
// block 128 (2 waves), thread t handles cols [t*8, t*8+8), head h0 = t>>5.
__global__ __launch_bounds__(128) void k_gat_fused(
    const u16* __restrict__ hw, const int* __restrict__ row_start,
    const int* __restrict__ csr_src, const float* __restrict__ es,
    const float* __restrict__ ed, const float* __restrict__ bias,
    const u16* __restrict__ gcn, const float* __restrict__ g,
    const float* __restrict__ b, u16* __restrict__ out)
{
  __shared__ float4 alph[ACAP];
  __shared__ float xch[8];
  int d = blockIdx.x, t = threadIdx.x, wv = t>>6, lane = t&63;
  int beg = row_start[d], end = row_start[d+1], deg = end-beg;
  float4 edq = *(const float4*)(ed + (size_t)d*4);
  float4 esq = *(const float4*)(es + (size_t)d*4);
  float edv[4] = {edq.x,edq.y,edq.z,edq.w};
  float esv[4] = {esq.x,esq.y,esq.z,esq.w};
  float eself[4], m[4];
#pragma unroll
  for (int h=0;h<4;h++){
    float e = esv[h] + edv[h];
    eself[h] = (e>0.f)? e : NEG_SLOPE*e;
    m[h] = eself[h];
  }
  // pass 1: max over in-edges (128-thread strided)
  for (int j=beg+t; j<end; j+=128){
    int s = csr_src[j];
    float4 qv = *(const float4*)(es + (size_t)s*4);
    float qa[4] = {qv.x,qv.y,qv.z,qv.w};
#pragma unroll
    for (int h=0;h<4;h++){
      float e = qa[h]+edv[h]; e = (e>0.f)? e : NEG_SLOPE*e;
      m[h] = fmaxf(m[h], e);
    }
  }
#pragma unroll
  for (int h=0;h<4;h++) m[h] = warp_max(m[h]);
  if (lane==0) ((float4*)xch)[wv] = make_float4(m[0],m[1],m[2],m[3]);
  __syncthreads();
  {
    float4 m0 = ((float4*)xch)[0], m1 = ((float4*)xch)[1];
    m[0]=fmaxf(m0.x,m1.x); m[1]=fmaxf(m0.y,m1.y);
    m[2]=fmaxf(m0.z,m1.z); m[3]=fmaxf(m0.w,m1.w);
  }
  __syncthreads();
  // pass 2: sum of exp, cache p in LDS if it fits
  bool fits = (deg <= ACAP);
  float sum[4] = {0.f,0.f,0.f,0.f};
  for (int j=beg+t; j<end; j+=128){
    int s = csr_src[j];
    float4 qv = *(const float4*)(es + (size_t)s*4);
    float qa[4] = {qv.x,qv.y,qv.z,qv.w}, p[4];
#pragma unroll
    for (int h=0;h<4;h++){
      float e = qa[h]+edv[h]; e = (e>0.f)? e : NEG_SLOPE*e;
      p[h] = expf(e-m[h]); sum[h]+=p[h];
    }
    if (fits) alph[j-beg] = make_float4(p[0],p[1],p[2],p[3]);
  }
#pragma unroll
  for (int h=0;h<4;h++) sum[h]=warp_sum(sum[h]);
  if (lane==0) ((float4*)xch)[wv] = make_float4(sum[0],sum[1],sum[2],sum[3]);
  __syncthreads();
  float rsm[4], swt[4];
  {
    float4 s0=((float4*)xch)[0], s1=((float4*)xch)[1];
    float sa[4] = {s0.x+s1.x, s0.y+s1.y, s0.z+s1.z, s0.w+s1.w};
#pragma unroll
    for (int h=0;h<4;h++){
      float pe = expf(eself[h]-m[h]);
      rsm[h] = 1.f/(sa[h]+pe);
      swt[h] = pe*rsm[h];
    }
  }
  // aggregation (unroll-4 gathers)
  int c0 = t*8, h0 = t>>5;
  u16x8 sv = *(const u16x8*)(hw + (size_t)d*HD + c0);
  float acc[8];
#pragma unroll
  for (int i=0;i<8;i++) acc[i] = swt[h0]*b2f(sv[i]);
  float mh = m[h0], rh = rsm[h0], edh = edv[h0];
  if (fits){
    int j = beg;
    for (; j+4 <= end; j += 4){
      int s0=csr_src[j], s1=csr_src[j+1], s2=csr_src[j+2], s3=csr_src[j+3];
      u16x8 r0 = *(const u16x8*)(hw + (size_t)s0*HD + c0);
      u16x8 r1 = *(const u16x8*)(hw + (size_t)s1*HD + c0);
      u16x8 r2 = *(const u16x8*)(hw + (size_t)s2*HD + c0);
      u16x8 r3 = *(const u16x8*)(hw + (size_t)s3*HD + c0);
      float a0 = ((const float*)&alph[j-beg  ])[h0] * rh;
      float a1 = ((const float*)&alph[j-beg+1])[h0] * rh;
      float a2 = ((const float*)&alph[j-beg+2])[h0] * rh;
      float a3 = ((const float*)&alph[j-beg+3])[h0] * rh;
#pragma unroll
      for (int i=0;i<8;i++){
        acc[i] = fmaf(a0, b2f(r0[i]), acc[i]);
        acc[i] = fmaf(a1, b2f(r1[i]), acc[i]);
        acc[i] = fmaf(a2, b2f(r2[i]), acc[i]);
        acc[i] = fmaf(a3, b2f(r3[i]), acc[i]);
      }
    }
    for (; j<end; ++j){
      int s = csr_src[j];
      float av = ((const float*)&alph[j-beg])[h0] * rh;
      u16x8 rv = *(const u16x8*)(hw + (size_t)s*HD + c0);
#pragma unroll
      for (int i=0;i<8;i++) acc[i] = fmaf(av, b2f(rv[i]), acc[i]);
    }
  } else {
    for (int j=beg; j<end; ++j){
      int s = csr_src[j];
      float e = es[(size_t)s*4+h0] + edh; e = (e>0.f)? e : NEG_SLOPE*e;
      float av = expf(e-mh)*rh;
      u16x8 rv = *(const u16x8*)(hw + (size_t)s*HD + c0);
#pragma unroll
      for (int i=0;i<8;i++) acc[i] = fmaf(av, b2f(rv[i]), acc[i]);
    }
  }
  // bias + residual (bf16) + LayerNorm + ReLU
  float4 bv0 = *(const float4*)(bias + c0), bv1 = *(const float4*)(bias + c0 + 4);
  u16x8 gv = *(const u16x8*)(gcn + (size_t)d*HD + c0);
  float ba8[8] = {bv0.x,bv0.y,bv0.z,bv0.w,bv1.x,bv1.y,bv1.z,bv1.w};
  float xv[8];
#pragma unroll
  for (int i=0;i<8;i++) xv[i] = acc[i] + ba8[i] + b2f(gv[i]);
  float ssum=0.f, ssq=0.f;
#pragma unroll
  for (int i=0;i<8;i++){ ssum += xv[i]; ssq = fmaf(xv[i], xv[i], ssq); }
  ssum = warp_sum(ssum); ssq = warp_sum(ssq);
  __syncthreads();   // protect xch reuse
  if (lane==0){ xch[wv]=ssum; xch[2+wv]=ssq; }
  __syncthreads();
  ssum = xch[0]+xch[1]; ssq = xch[2]+xch[3];
  float mean = ssum * (1.f/HD);
  float var  = ssq * (1.f/HD) - mean*mean;
  float rsln = rsqrtf(var + LN_EPS);
  float4 gg0 = *(const float4*)(g + c0), gg1 = *(const float4*)(g + c0 + 4);
  float4 bb0 = *(const float4*)(b + c0), bb1 = *(const float4*)(b + c0 + 4);
  float ga[8] = {gg0.x,gg0.y,gg0.z,gg0.w,gg1.x,gg1.y,gg1.z,gg1.w};
  float ba[8] = {bb0.x,bb0.y,bb0.z,bb0.w,bb1.x,bb1.y,bb1.z,bb1.w};
  u16x8 ob;
#pragma unroll
  for (int i=0;i<8;i++)
    ob[i] = f2b(fmaxf((xv[i]-mean)*rsln*ga[i] + ba[i], 0.f));
  *(u16x8*)(out + (size_t)d*HD + c0) = ob;
}

// ---------------- cosine sims (norms computed inline, no k_norms_b) --------
__global__ __launch_bounds__(256) void k_sims_csr(
    const u16* __restrict__ comb,
    const int* __restrict__ row_start, const int* __restrict__ csr_src,
    const int* __restrict__ csr_eid, float* __restrict__ out, int E)
{
  int d = blockIdx.x;
  int w = threadIdx.x>>6, lane = threadIdx.x&63;
  int g = lane>>4, l = lane&15;          // pair group, lane-in-group
  int beg = row_start[d], end = row_start[d+1];
  if (beg >= end) return;
  const int baseA[4] = {IN, IN+TD,   IN+2*TD, IN+3*TD};   // src: bio, exp, needs, goals
  const int baseB[4] = {IN, IN+2*TD, IN+TD,   IN+3*TD};   // dst: bio, needs, exp, goals
  // dst-side 48 cols for this lane (held across the edge loop)
  const u16* bp = comb + (size_t)d*CD + baseB[g] + l*8;
  float bf[48];
  float nbss = 0.f;
#pragma unroll
  for (int i=0;i<6;i++){
    u16x8 v = *(const u16x8*)(bp + i*128);
#pragma unroll
    for (int k=0;k<8;k++){
      float f = b2f(v[k]);
      bf[i*8+k] = f;
      nbss = fmaf(f, f, nbss);
    }
  }
  nbss += __shfl_xor(nbss,1); nbss += __shfl_xor(nbss,2);
  nbss += __shfl_xor(nbss,4); nbss += __shfl_xor(nbss,8);
  float rnb = 1.f / fmaxf(sqrtf(nbss), COS_EPS);
  for (int j = beg + w; j < end; j += 4){
    int s = csr_src[j];
    const u16* ap = comb + (size_t)s*CD + baseA[g] + l*8;
    float dot = 0.f, ass = 0.f;
#pragma unroll
    for (int i=0;i<6;i++){
      u16x8 v = *(const u16x8*)(ap + i*128);
#pragma unroll
      for (int k=0;k<8;k++){
        float f = b2f(v[k]);
        dot = fmaf(f, bf[i*8+k], dot);
        ass = fmaf(f, f, ass);
      }
    }
    dot += __shfl_xor(dot,1); dot += __shfl_xor(dot,2);
    dot += __shfl_xor(dot,4); dot += __shfl_xor(dot,8);
    ass += __shfl_xor(ass,1); ass += __shfl_xor(ass,2);
    ass += __shfl_xor(ass,4); ass += __shfl_xor(ass,8);
    if (l==0){
      float na = fmaxf(sqrtf(ass), COS_EPS);
      out[(size_t)g*E + csr_eid[j]] = dot * rnb / na;
    }
  }
}

// ---------------- skills / compat ------------------------------------------
__global__ __launch_bounds__(128) void k_skill_mean_b(
    const float* __restrict__ semb, const int* __restrict__ id1,
    const int* __restrict__ id2, u16* __restrict__ comb)
{
  int b = blockIdx.x, c = threadIdx.x;
  float s1=0.f, s2=0.f;
  for (int k=0;k<KSK;k++){
    s1 += semb[(size_t)id1[b*KSK+k]*SDIM + c];
    s2 += semb[(size_t)id2[b*KSK+k]*SDIM + c];
  }
  comb[(size_t)b*256 + c]       = f2b(s1*(1.f/KSK));
  comb[(size_t)b*256 + 128 + c] = f2b(s2*(1.f/KSK));
}

__global__ __launch_bounds__(256) void k_compat(
    const float* __restrict__ hidden, const float* __restrict__ w2,
    const float* __restrict__ b2, float* __restrict__ out)
{
  __shared__ float red[4];
  int bi = blockIdx.x, t = threadIdx.x;
  float s = 0.f;
  for (int c=t;c<HD;c+=256) s = fmaf(hidden[(size_t)bi*HD+c], w2[c], s);
  s = warp_sum(s);
  if ((t&63)==0) red[t>>6] = s;
  __syncthreads();
  if (t==0){
    float tot = red[0]+red[1]+red[2]+red[3] + b2[0];
    out[bi] = 1.f/(1.f+expf(-tot));
  }
}

// ---------------------------------------------------------------------------
extern "C" void kernel_launch(void* const* d_in, const int* in_sizes, int n_in,
                              void* d_out, int out_size, void* d_ws, size_t ws_size,
                              hipStream_t stream)
{
  const float* x         = (const float*)d_in[0];
  const int*   eidx      = (const int*)d_in[1];
  const int*   dom_ids   = (const int*)d_in[2];
  const int*   sk1       = (const int*)d_in[3];
  const int*   sk2       = (const int*)d_in[4];
  const float* bio_emb   = (const float*)d_in[5];
  const float* bio_w     = (const float*)d_in[6];
  const float* bio_b     = (const float*)d_in[7];
  const float* exp_emb   = (const float*)d_in[8];
  const float* exp_w     = (const float*)d_in[9];
  const float* exp_b     = (const float*)d_in[10];
  const float* needs_emb = (const float*)d_in[11];
  const float* needs_w   = (const float*)d_in[12];
  const float* needs_b   = (const float*)d_in[13];
  const float* goals_emb = (const float*)d_in[14];
  const float* goals_w   = (const float*)d_in[15];
  const float* goals_b   = (const float*)d_in[16];
  const float* gcn_w0 = (const float*)d_in[17];
  const float* gcn_b0 = (const float*)d_in[18];
  const float* gat_w0 = (const float*)d_in[19];
  const float* gat_as0= (const float*)d_in[20];
  const float* gat_ad0= (const float*)d_in[21];
  const float* gat_b0 = (const float*)d_in[22];
  const float* ln_g0  = (const float*)d_in[23];
  const float* ln_b0  = (const float*)d_in[24];
  const float* gcn_w1 = (const float*)d_in[25];
  const float* gcn_b1 = (const float*)d_in[26];
  const float* gat_w1 = (const float*)d_in[27];
  const float* gat_as1= (const float*)d_in[28];
  const float* gat_ad1= (const float*)d_in[29];
  const float* gat_b1 = (const float*)d_in[30];
  const float* ln_g1  = (const float*)d_in[31];
  const float* ln_b1  = (const float*)d_in[32];
  const float* dom_emb= (const float*)d_in[33];
  const float* dom_w  = (const float*)d_in[34];
  const float* dom_b  = (const float*)d_in[35];
  const float* skill_emb = (const float*)d_in[36];
  const float* c_w1   = (const float*)d_in[37];
  const float* c_b1   = (const float*)d_in[38];
  const float* c_w2   = (const float*)d_in[39];
  const float* c_b2   = (const float*)d_in[40];

  const int E   = in_sizes[1] / 2;
  const int Bsz = in_sizes[3] / KSK;
  const int* srcp = eidx;
  const int* dstp = eidx + E;

  // ---- workspace bump allocator (256B aligned) ----
  char* wsp = (char*)d_ws;
  size_t off = 0;
  auto alloc = [&](size_t bytes)->void*{
    void* p = wsp + off;
    off += (bytes + 255) & ~(size_t)255;
    return p;
  };
  u16*   combined_b = (u16*)alloc((size_t)MP*CD*2);  // 67.3 MB (dead after GCN0 gemm)
  u16*   P0b  = (u16*) alloc((size_t)MP*HD*2);       // xw    (bf16)
  u16*   P1b  = (u16*) alloc((size_t)MP*HD*2);       // x_gcn (bf16: GAT A + LN residual)
  u16*   Rh   = (u16*) alloc((size_t)MP*HD*2);       // layer output bf16
  u16*   wt_bio   = (u16*)alloc((size_t)TD*TD*2);
  u16*   wt_exp   = (u16*)alloc((size_t)TD*TD*2);
  u16*   wt_needs = (u16*)alloc((size_t)TD*TD*2);
  u16*   wt_goals = (u16*)alloc((size_t)TD*TD*2);
  u16*   w_gcn0t  = (u16*)alloc((size_t)HD*CD*2);
  u16*   w_gat0t  = (u16*)alloc((size_t)HD*HD*2);
  u16*   w_gcn1t  = (u16*)alloc((size_t)HD*HD*2);
  u16*   w_gat1t  = (u16*)alloc((size_t)HD*HD*2);
  u16*   w_domt   = (u16*)alloc((size_t)HD*HD*2);
  u16*   w_c1t    = (u16*)alloc((size_t)HD*2*SDIM*2);
  u16*   comb_b   = (u16*)alloc((size_t)Bsz*2*SDIM*2);
  float* hidden   = (float*)alloc((size_t)Bsz*HD*4);
  float* es      = (float*)alloc((size_t)NN*4*4);
  float* ed      = (float*)alloc((size_t)NN*4*4);
  float* dinv    = (float*)alloc((size_t)NN*4);
  int*   indeg   = (int*)  alloc((size_t)NN*4);
  int*   row_st  = (int*)  alloc((size_t)(NN+1)*4);
  int*   cursor  = (int*)  alloc((size_t)NN*4);
  int*   csr_src = (int*)  alloc((size_t)E*4);
  int*   csr_eid = (int*)  alloc((size_t)E*4);

  // overlay: hw (bf16 GAT gemm output) reuses combined_b once it's dead
  u16* Rhwb = combined_b;

  float* out0       = (float*)d_out;                  // domain_embeddings [NN,HD]
  float* out_compat = out0 + (size_t)NN*HD;           // [Bsz]
  float* out_sims   = out_compat + Bsz;               // 4 x [E] contiguous

  dim3 blk(256);

  // 0. CSR by dst
  hipMemsetAsync(indeg, 0, (size_t)NN*sizeof(int), stream);
  k_hist<<<dim3((E+255)/256), blk, 0, stream>>>(dstp, indeg, E);
  k_scan<<<dim3(1), dim3(1024), 0, stream>>>(indeg, row_st, cursor, dinv, NN);
  k_scatter<<<dim3((E+255)/256), blk, 0, stream>>>(srcp, dstp, cursor, csr_src, csr_eid, E);

  // 1. weight transposes -> bf16 [N][K] (batched)
  k_transb4<<<dim3(TD/32, TD/32, 4), blk, 0, stream>>>(
      bio_w, exp_w, needs_w, goals_w, wt_bio, wt_exp, wt_needs, wt_goals, TD, TD);
  k_transb4<<<dim3(HD/32, HD/32, 4), blk, 0, stream>>>(
      gat_w0, gcn_w1, gat_w1, dom_w, w_gat0t, w_gcn1t, w_gat1t, w_domt, HD, HD);
  k_transb4<<<dim3(HD/32, CD/32, 1), blk, 0, stream>>>(
      gcn_w0, gcn_w0, gcn_w0, gcn_w0, w_gcn0t, w_gcn0t, w_gcn0t, w_gcn0t, CD, HD);
  k_transb4<<<dim3(HD/32, (2*SDIM)/32, 1), blk, 0, stream>>>(
      c_w1, c_w1, c_w1, c_w1, w_c1t, w_c1t, w_c1t, w_c1t, 2*SDIM, HD);

  // 2. combined_b = [x | bio_f | exp_f | needs_f | goals_f] (bf16)
  //    text GEMM reads the f32 embeddings DIRECTLY (no f2b pass, no Aact)
  k_copyx_b<<<dim3((NN*IN)/8/256), blk, 0, stream>>>(x, combined_b);
  k_gemm_text<<<dim3(TD/128, MP/128, 4), blk, 0, stream>>>(
      bio_emb, exp_emb, needs_emb, goals_emb,
      wt_bio, wt_exp, wt_needs, wt_goals,
      bio_b, exp_b, needs_b, goals_b,
      combined_b + IN, CD, (long)TD, NN, TD);

  // 3. cosine sims (dst-stationary, CSR order; norms inline)
  k_sims_csr<<<dim3(NN), blk, 0, stream>>>(combined_b, row_st, csr_src,
                                           csr_eid, out_sims, E);

  // 4. skill / compat path
  k_skill_mean_b<<<dim3(Bsz), dim3(128), 0, stream>>>(skill_emb, sk1, sk2, comb_b);
  k_gemm_bf16<<<dim3(HD/128, Bsz/128, 1), blk, 0, stream>>>(
      comb_b, 0, w_c1t, w_c1t, w_c1t, w_c1t, c_b1, c_b1, c_b1, c_b1,
      hidden, HD, nullptr, 0, 0, nullptr, nullptr, Bsz, 2*SDIM, 1);
  k_compat<<<dim3(Bsz), blk, 0, stream>>>(hidden, c_w2, c_b2, out_compat);

  dim3 g_h(HD/128, MP/128, 1);

  // 5. layer 0
  k_gemm_bf16<<<g_h, blk, 0, stream>>>(
      combined_b, 0, w_gcn0t, w_gcn0t, w_gcn0t, w_gcn0t,
      nullptr, nullptr, nullptr, nullptr,
      nullptr, 0, P0b, HD, 0, nullptr, nullptr, NN, CD, 0);
  k_gcn_agg<<<dim3(NN), dim3(128), 0, stream>>>(P0b, row_st, csr_src, dinv, gcn_b0, P1b);
  k_gemm_bf16<<<g_h, blk, 0, stream>>>(
      P1b, 0, w_gat0t, w_gat0t, w_gat0t, w_gat0t,
      nullptr, nullptr, nullptr, nullptr,
      nullptr, 0, Rhwb, HD, 0, nullptr, nullptr, NN, HD, 0);
  k_es_ed<<<dim3(NN), blk, 0, stream>>>(Rhwb, gat_as0, gat_ad0, es, ed);
  k_gat_fused<<<dim3(NN), dim3(128), 0, stream>>>(Rhwb, row_st, csr_src, es, ed,
                                                  gat_b0, P1b, ln_g0, ln_b0, Rh);

  // 6. layer 1
  k_gemm_bf16<<<g_h, blk, 0, stream>>>(
      Rh, 0, w_gcn1t, w_gcn1t, w_gcn1t, w_gcn1t,
      nullptr, nullptr, nullptr, nullptr,
      nullptr, 0, P0b, HD, 0, nullptr, nullptr, NN, HD, 0);
  k_gcn_agg<<<dim3(NN), dim3(128), 0, stream>>>(P0b, row_st, csr_src, dinv, gcn_b1, P1b);
  k_gemm_bf16<<<g_h, blk, 0, stream>>>(
      P1b, 0, w_gat1t, w_gat1t, w_gat1t, w_gat1t,
      nullptr, nullptr, nullptr, nullptr,
      nullptr, 0, Rhwb, HD, 0, nullptr, nullptr, NN, HD, 0);
  k_es_ed<<<dim3(NN), blk, 0, stream>>>(Rhwb, gat_as1, gat_ad1, es, ed);
  k_gat_fused<<<dim3(NN), dim3(128), 0, stream>>>(Rhwb, row_st, csr_src, es, ed,
                                                  gat_b1, P1b, ln_g1, ln_b1, Rh);

  // 7. domain embeddings (dom_emb gather fused into epilogue)
  k_gemm_bf16<<<g_h, blk, 0, stream>>>(
      Rh, 0, w_domt, w_domt, w_domt, w_domt,
      dom_b, dom_b, dom_b, dom_b,
      out0, HD, nullptr, 0, 0, dom_emb, dom_ids, NN, HD, 0);
}